// Round 6
// baseline (552.840 us; speedup 1.0000x reference)
//
#include <hip/hip_runtime.h>
#include <hip/hip_fp16.h>

// LightGCN forward: acc = sum over layers of (A^l @ X), A sparse COO (src,dst,w).
// Build dst-sorted CSR once per launch, atomic-free and deterministic:
//   lg_tilehist : per-tile LDS histogram -> tcnt[bucket][tile]  (bucket-major)
//   lg_flatscan : ONE exclusive scan over tcnt -> tbase (run bases + bucket bases)
//   lg_scatter2 : scatter edges into contiguous per-(tile,bucket) runs (LDS cursors)
//   lg_bfinal   : per-bucket (512-node) LDS counting sort -> dst-sorted edata + rowptr
// Then 3 gather SpMM layers; layer embeddings staged FP16, accumulator FP32.

#define D 64
#define BSH 9
#define BW 512            // nodes per bucket = 1<<BSH
#define PTILE 16384       // edges per partition tile

// fp32 -> fp16 conversion (4 floats / thread)
__global__ void lg_f2h(const float* __restrict__ in, __half* __restrict__ out, int n4) {
    int i = blockIdx.x * blockDim.x + threadIdx.x;
    int st = gridDim.x * blockDim.x;
    const float4* src = (const float4*)in;
    uint2* dst = (uint2*)out;
    for (; i < n4; i += st) {
        float4 v = src[i];
        __half2 a = __floats2half2_rn(v.x, v.y);
        __half2 b = __floats2half2_rn(v.z, v.w);
        uint2 u;
        u.x = *reinterpret_cast<unsigned int*>(&a);
        u.y = *reinterpret_cast<unsigned int*>(&b);
        dst[i] = u;
    }
}

// per-tile bucket histogram -> tcnt[b*ntiles + t]
__global__ __launch_bounds__(1024) void lg_tilehist(const int* __restrict__ edst,
                                                    int* __restrict__ tcnt,
                                                    int E, int NB, int ntiles) {
    extern __shared__ int cnt[];   // NB ints
    int t = blockIdx.x;
    int lo = t * PTILE;
    int hi = lo + PTILE; if (hi > E) hi = E;
    for (int i = threadIdx.x; i < NB; i += 1024) cnt[i] = 0;
    __syncthreads();
    for (int i = lo + threadIdx.x; i < hi; i += 1024)
        atomicAdd(&cnt[edst[i] >> BSH], 1);
    __syncthreads();
    for (int b = threadIdx.x; b < NB; b += 1024)
        tcnt[b * ntiles + t] = cnt[b];
}

// single-block exclusive scan over NT = NB*ntiles entries (bucket-major)
__global__ __launch_bounds__(1024) void lg_flatscan(const int* __restrict__ tcnt,
                                                    int* __restrict__ tbase,
                                                    int NT, int E,
                                                    int* __restrict__ rowptr, int n_nodes) {
    __shared__ int lds[1024];
    int tid = threadIdx.x;
    int per = (NT + 1023) >> 10;
    int lo = tid * per; if (lo > NT) lo = NT;
    int hi = lo + per;  if (hi > NT) hi = NT;
    int sum = 0;
    for (int i = lo; i < hi; ++i) sum += tcnt[i];
    lds[tid] = sum;
    __syncthreads();
    for (int off = 1; off < 1024; off <<= 1) {
        int v = (tid >= off) ? lds[tid - off] : 0;
        __syncthreads();
        lds[tid] += v;
        __syncthreads();
    }
    int run = lds[tid] - sum;
    for (int i = lo; i < hi; ++i) {
        tbase[i] = run;
        run += tcnt[i];
    }
    if (tid == 0) rowptr[n_nodes] = E;
}

// scatter edges into their (tile,bucket) runs; LDS cursors, no global atomics.
// record: {src | (dst&511)<<18, w_bits}; src<2^18 ok for n_nodes=150000.
__global__ __launch_bounds__(1024) void lg_scatter2(const int* __restrict__ esrc,
                                                    const int* __restrict__ edst,
                                                    const float* __restrict__ ew,
                                                    const int* __restrict__ tbase,
                                                    int2* __restrict__ bbuf,
                                                    int E, int NB, int ntiles) {
    extern __shared__ int cur[];   // NB ints
    int t = blockIdx.x;
    int lo = t * PTILE;
    int hi = lo + PTILE; if (hi > E) hi = E;
    for (int b = threadIdx.x; b < NB; b += 1024) cur[b] = tbase[b * ntiles + t];
    __syncthreads();
    for (int i = lo + threadIdx.x; i < hi; i += 1024) {
        int d = edst[i];
        int b = d >> BSH;
        int p = atomicAdd(&cur[b], 1);
        bbuf[p] = make_int2(esrc[i] | ((d & (BW - 1)) << 18), __float_as_int(ew[i]));
    }
}

// per-bucket LDS counting sort (512 local nodes) -> dst-sorted edata + rowptr
__global__ __launch_bounds__(1024) void lg_bfinal(const int2* __restrict__ bbuf,
                                                  const int* __restrict__ tbase,
                                                  int2* __restrict__ edata,
                                                  int* __restrict__ rowptr,
                                                  int n_nodes, int NB, int ntiles, int E) {
    __shared__ int cnt[BW];
    __shared__ int cur[BW];
    __shared__ int psum[BW];
    int b = blockIdx.x;
    int s = tbase[b * ntiles];
    int e = (b == NB - 1) ? E : tbase[(b + 1) * ntiles];
    int tid = threadIdx.x;
    if (tid < BW) cnt[tid] = 0;
    __syncthreads();
    for (int i = s + tid; i < e; i += 1024)
        atomicAdd(&cnt[((unsigned)bbuf[i].x >> 18) & (BW - 1)], 1);
    __syncthreads();
    if (tid < BW) psum[tid] = cnt[tid];
    __syncthreads();
    for (int off = 1; off < BW; off <<= 1) {
        int v = 0;
        if (tid < BW && tid >= off) v = psum[tid - off];
        __syncthreads();
        if (tid < BW) psum[tid] += v;
        __syncthreads();
    }
    if (tid < BW) {
        int excl = psum[tid] - cnt[tid];
        cur[tid] = excl;
        int node = b * BW + tid;
        if (node < n_nodes) rowptr[node] = s + excl;
    }
    __syncthreads();
    for (int i = s + tid; i < e; i += 1024) {
        int2 ed = bbuf[i];
        int loc = ((unsigned)ed.x >> 18) & (BW - 1);
        int p = s + atomicAdd(&cur[loc], 1);
        edata[p] = make_int2(ed.x & 0x3FFFF, ed.y);
    }
}

// gather SpMM (fp16 x): wave per dst node, quarter-wave per edge.
// lane = (q = edge slot 0..3, c = 8-byte chunk 0..15): each lane loads 4 halves.
template <bool FIRST, bool LAST>
__global__ __launch_bounds__(256) void lg_gather(const int2* __restrict__ edata,
                                                 const int* __restrict__ rowptr,
                                                 const __half* __restrict__ x,
                                                 __half* __restrict__ y,
                                                 float* __restrict__ acc,
                                                 const float* __restrict__ ini,
                                                 int n_nodes) {
    int wid = (blockIdx.x * blockDim.x + threadIdx.x) >> 6;
    int lane = threadIdx.x & 63;
    if (wid >= n_nodes) return;
    int q = lane >> 4, c = lane & 15;
    int start = rowptr[wid], end = rowptr[wid + 1];
    float ax = 0.f, ay = 0.f, az = 0.f, aw = 0.f;
    int base = start;
    for (; base + 16 <= end; base += 16) {
        int2 e0 = edata[base + q];
        int2 e1 = edata[base + 4 + q];
        int2 e2 = edata[base + 8 + q];
        int2 e3 = edata[base + 12 + q];
        uint2 u0 = *((const uint2*)(x + (size_t)e0.x * D) + c);
        uint2 u1 = *((const uint2*)(x + (size_t)e1.x * D) + c);
        uint2 u2 = *((const uint2*)(x + (size_t)e2.x * D) + c);
        uint2 u3 = *((const uint2*)(x + (size_t)e3.x * D) + c);
        float w0 = __int_as_float(e0.y), w1 = __int_as_float(e1.y);
        float w2 = __int_as_float(e2.y), w3 = __int_as_float(e3.y);
        {
            float2 f0 = __half22float2(*reinterpret_cast<__half2*>(&u0.x));
            float2 f1 = __half22float2(*reinterpret_cast<__half2*>(&u0.y));
            ax += w0 * f0.x; ay += w0 * f0.y; az += w0 * f1.x; aw += w0 * f1.y;
        }
        {
            float2 f0 = __half22float2(*reinterpret_cast<__half2*>(&u1.x));
            float2 f1 = __half22float2(*reinterpret_cast<__half2*>(&u1.y));
            ax += w1 * f0.x; ay += w1 * f0.y; az += w1 * f1.x; aw += w1 * f1.y;
        }
        {
            float2 f0 = __half22float2(*reinterpret_cast<__half2*>(&u2.x));
            float2 f1 = __half22float2(*reinterpret_cast<__half2*>(&u2.y));
            ax += w2 * f0.x; ay += w2 * f0.y; az += w2 * f1.x; aw += w2 * f1.y;
        }
        {
            float2 f0 = __half22float2(*reinterpret_cast<__half2*>(&u3.x));
            float2 f1 = __half22float2(*reinterpret_cast<__half2*>(&u3.y));
            ax += w3 * f0.x; ay += w3 * f0.y; az += w3 * f1.x; aw += w3 * f1.y;
        }
    }
    for (; base < end; base += 4) {
        int idx = base + q;
        if (idx < end) {
            int2 e0 = edata[idx];
            float w0 = __int_as_float(e0.y);
            uint2 u0 = *((const uint2*)(x + (size_t)e0.x * D) + c);
            float2 f0 = __half22float2(*reinterpret_cast<__half2*>(&u0.x));
            float2 f1 = __half22float2(*reinterpret_cast<__half2*>(&u0.y));
            ax += w0 * f0.x; ay += w0 * f0.y; az += w0 * f1.x; aw += w0 * f1.y;
        }
    }
    ax += __shfl_xor(ax, 16); ax += __shfl_xor(ax, 32);
    ay += __shfl_xor(ay, 16); ay += __shfl_xor(ay, 32);
    az += __shfl_xor(az, 16); az += __shfl_xor(az, 32);
    aw += __shfl_xor(aw, 16); aw += __shfl_xor(aw, 32);
    if (lane < 16) {
        size_t o = (size_t)wid * D + (size_t)c * 4;
        if (!LAST) {
            __half2 h0 = __floats2half2_rn(ax, ay);
            __half2 h1 = __floats2half2_rn(az, aw);
            uint2 u;
            u.x = *reinterpret_cast<unsigned int*>(&h0);
            u.y = *reinterpret_cast<unsigned int*>(&h1);
            *(uint2*)(y + o) = u;
        }
        if (FIRST) {
            float4 iv = *(const float4*)(ini + o);
            *(float4*)(acc + o) = make_float4(iv.x + ax, iv.y + ay, iv.z + az, iv.w + aw);
        } else {
            float4 av = *(float4*)(acc + o);
            *(float4*)(acc + o) = make_float4(av.x + ax, av.y + ay, av.z + az, av.w + aw);
        }
    }
}

// fallback (atomic scatter path, only if ws too small)
__global__ void lg_init_kernel(const float* __restrict__ ini, float* __restrict__ cur,
                               float* __restrict__ acc, float* __restrict__ nxt, int n4) {
    int i = blockIdx.x * blockDim.x + threadIdx.x;
    int stride = gridDim.x * blockDim.x;
    const float4* s = (const float4*)ini;
    float4* c = (float4*)cur; float4* a = (float4*)acc; float4* z = (float4*)nxt;
    float4 zero = make_float4(0.f, 0.f, 0.f, 0.f);
    for (; i < n4; i += stride) { float4 v = s[i]; c[i] = v; a[i] = v; z[i] = zero; }
}

__global__ void lg_spmm_kernel(const int* __restrict__ esrc, const int* __restrict__ edst,
                               const float* __restrict__ ew, const float* __restrict__ x,
                               float* __restrict__ y, int E) {
    int tid = blockIdx.x * blockDim.x + threadIdx.x;
    int e = tid >> 4;
    if (e >= E) return;
    int l = (tid & 15) << 2;
    int s = esrc[e]; int d = edst[e]; float w = ew[e];
    float4 v = *(const float4*)(x + s * D + l);
    float* yp = y + d * D + l;
    unsafeAtomicAdd(yp + 0, w * v.x);
    unsafeAtomicAdd(yp + 1, w * v.y);
    unsafeAtomicAdd(yp + 2, w * v.z);
    unsafeAtomicAdd(yp + 3, w * v.w);
}

__global__ void lg_addzero_kernel(float* __restrict__ acc, const float* __restrict__ nxt,
                                  float* __restrict__ zbuf, int n4) {
    int i = blockIdx.x * blockDim.x + threadIdx.x;
    int stride = gridDim.x * blockDim.x;
    float4* a = (float4*)acc; const float4* n = (const float4*)nxt; float4* z = (float4*)zbuf;
    float4 zero = make_float4(0.f, 0.f, 0.f, 0.f);
    for (; i < n4; i += stride) {
        float4 av = a[i]; float4 nv = n[i];
        av.x += nv.x; av.y += nv.y; av.z += nv.z; av.w += nv.w;
        a[i] = av; z[i] = zero;
    }
}

extern "C" void kernel_launch(void* const* d_in, const int* in_sizes, int n_in,
                              void* d_out, int out_size, void* d_ws, size_t ws_size,
                              hipStream_t stream) {
    const float* ini  = (const float*)d_in[0];
    const int*   esrc = (const int*)d_in[1];
    const int*   edst = (const int*)d_in[2];
    const float* ew   = (const float*)d_in[3];

    int n_nodes = in_sizes[0] / D;     // 150000
    int E       = in_sizes[1];         // 4.8M
    int NB      = (n_nodes + BW - 1) >> BSH;        // 293
    int ntiles  = (E + PTILE - 1) / PTILE;          // 293
    int NT      = NB * ntiles;                      // 85849

    size_t hBytes     = ((size_t)n_nodes * D * sizeof(__half) + 255) & ~(size_t)255;  // 19.2 MB
    size_t edataBytes = (size_t)E * sizeof(int2);                                     // 38.4 MB
    size_t ptrBytes   = (((size_t)n_nodes + 1) * 4 + 15) & ~(size_t)15;
    size_t tcntBytes  = (((size_t)NT * 4) + 15) & ~(size_t)15;
    size_t need = 2 * hBytes + 2 * edataBytes + ptrBytes + 2 * tcntBytes + 64;

    float* acc = (float*)d_out;

    if (ws_size >= need) {
        char* p = (char*)d_ws;
        __half* h0    = (__half*)p; p += hBytes;
        __half* h1    = (__half*)p; p += hBytes;
        int2*  edata  = (int2*)p;   p += edataBytes;
        int2*  bbuf   = (int2*)p;   p += edataBytes;
        int*   rowptr = (int*)p;    p += ptrBytes;
        int*   tcnt   = (int*)p;    p += tcntBytes;
        int*   tbase  = (int*)p;

        int n4 = n_nodes * D / 4;

        lg_f2h<<<2048, 256, 0, stream>>>(ini, h0, n4);
        lg_tilehist<<<ntiles, 1024, (size_t)NB * 4, stream>>>(edst, tcnt, E, NB, ntiles);
        lg_flatscan<<<1, 1024, 0, stream>>>(tcnt, tbase, NT, E, rowptr, n_nodes);
        lg_scatter2<<<ntiles, 1024, (size_t)NB * 4, stream>>>(esrc, edst, ew, tbase, bbuf, E, NB, ntiles);
        lg_bfinal<<<NB, 1024, 0, stream>>>(bbuf, tbase, edata, rowptr, n_nodes, NB, ntiles, E);

        int gblocks = (int)(((size_t)n_nodes * 64 + 255) / 256);
        lg_gather<true,  false><<<gblocks, 256, 0, stream>>>(edata, rowptr, h0, h1, acc, ini, n_nodes);
        lg_gather<false, false><<<gblocks, 256, 0, stream>>>(edata, rowptr, h1, h0, acc, ini, n_nodes);
        lg_gather<false, true ><<<gblocks, 256, 0, stream>>>(edata, rowptr, h0, h1, acc, ini, n_nodes);
    } else {
        int n4 = (n_nodes * D) / 4;
        float* cur = (float*)d_ws;
        float* nxt = cur + (size_t)n_nodes * D;
        lg_init_kernel<<<2048, 256, 0, stream>>>(ini, cur, acc, nxt, n4);
        int spmm_blocks = (E * 16 + 255) / 256;
        for (int layer = 0; layer < 3; ++layer) {
            lg_spmm_kernel<<<spmm_blocks, 256, 0, stream>>>(esrc, edst, ew, cur, nxt, E);
            lg_addzero_kernel<<<2048, 256, 0, stream>>>(acc, nxt, cur, n4);
            float* t = cur; cur = nxt; nxt = t;
        }
    }
}

// Round 7
// 453.515 us; speedup vs baseline: 1.2190x; 1.2190x over previous
//
#include <hip/hip_runtime.h>
#include <hip/hip_fp16.h>

// LightGCN forward: acc = sum over layers of (A^l @ X), A sparse COO (src,dst,w).
// Build dst-sorted CSR once per launch, atomic-free and deterministic:
//   lg_tilehist      : per-tile LDS histogram -> tcnt[bucket][tile]  (bucket-major)
//   lg_scan1/2/3     : hierarchical exclusive scan over tcnt -> tbase
//   lg_scatter2      : scatter edges into contiguous per-(tile,bucket) runs (LDS cursors)
//   lg_bfinal        : per-bucket (512-node) LDS counting sort -> dst-sorted edata + rowptr
// Then 3 gather SpMM layers; layer embeddings staged FP16, accumulator FP32.

#define D 64
#define BSH 9
#define BW 512            // nodes per bucket = 1<<BSH
#define PTILE 16384       // edges per partition tile

// fp32 -> fp16 conversion (4 floats / thread)
__global__ void lg_f2h(const float* __restrict__ in, __half* __restrict__ out, int n4) {
    int i = blockIdx.x * blockDim.x + threadIdx.x;
    int st = gridDim.x * blockDim.x;
    const float4* src = (const float4*)in;
    uint2* dst = (uint2*)out;
    for (; i < n4; i += st) {
        float4 v = src[i];
        __half2 a = __floats2half2_rn(v.x, v.y);
        __half2 b = __floats2half2_rn(v.z, v.w);
        uint2 u;
        u.x = *reinterpret_cast<unsigned int*>(&a);
        u.y = *reinterpret_cast<unsigned int*>(&b);
        dst[i] = u;
    }
}

// per-tile bucket histogram -> tcnt[b*ntiles + t]
__global__ __launch_bounds__(1024) void lg_tilehist(const int* __restrict__ edst,
                                                    int* __restrict__ tcnt,
                                                    int E, int NB, int ntiles) {
    extern __shared__ int cnt[];   // NB ints
    int t = blockIdx.x;
    int lo = t * PTILE;
    int hi = lo + PTILE; if (hi > E) hi = E;
    for (int i = threadIdx.x; i < NB; i += 1024) cnt[i] = 0;
    __syncthreads();
    for (int i = lo + threadIdx.x; i < hi; i += 1024)
        atomicAdd(&cnt[edst[i] >> BSH], 1);
    __syncthreads();
    for (int b = threadIdx.x; b < NB; b += 1024)
        tcnt[b * ntiles + t] = cnt[b];
}

// scan stage 1: per-block LDS scan of 1024 entries; exclusive -> tbase, total -> blksum
__global__ __launch_bounds__(1024) void lg_scan1(const int* __restrict__ tcnt,
                                                 int* __restrict__ tbase,
                                                 int* __restrict__ blksum, int NT) {
    __shared__ int lds[1024];
    int tid = threadIdx.x;
    int i = blockIdx.x * 1024 + tid;
    int v = (i < NT) ? tcnt[i] : 0;
    lds[tid] = v;
    __syncthreads();
    for (int off = 1; off < 1024; off <<= 1) {
        int t = (tid >= off) ? lds[tid - off] : 0;
        __syncthreads();
        lds[tid] += t;
        __syncthreads();
    }
    if (i < NT) tbase[i] = lds[tid] - v;
    if (tid == 1023) blksum[blockIdx.x] = lds[tid];
}

// scan stage 2: exclusive scan of block sums (nblk <= 128); also seeds rowptr[n]
__global__ __launch_bounds__(128) void lg_scan2(int* __restrict__ blksum, int nblk,
                                                int* __restrict__ rowptr, int n_nodes, int E) {
    __shared__ int lds[128];
    int tid = threadIdx.x;
    int v = (tid < nblk) ? blksum[tid] : 0;
    lds[tid] = v;
    __syncthreads();
    for (int off = 1; off < 128; off <<= 1) {
        int t = (tid >= off) ? lds[tid - off] : 0;
        __syncthreads();
        lds[tid] += t;
        __syncthreads();
    }
    if (tid < nblk) blksum[tid] = lds[tid] - v;   // exclusive
    if (tid == 0) rowptr[n_nodes] = E;
}

// scan stage 3: add block offsets
__global__ __launch_bounds__(1024) void lg_scan3(int* __restrict__ tbase,
                                                 const int* __restrict__ blksum, int NT) {
    int add = blksum[blockIdx.x];
    int i = blockIdx.x * 1024 + threadIdx.x;
    if (i < NT) tbase[i] += add;
}

// scatter edges into their (tile,bucket) runs; LDS cursors, no global atomics.
// record: {src | (dst&511)<<18, w_bits}; src<2^18 ok for n_nodes=150000.
__global__ __launch_bounds__(1024) void lg_scatter2(const int* __restrict__ esrc,
                                                    const int* __restrict__ edst,
                                                    const float* __restrict__ ew,
                                                    const int* __restrict__ tbase,
                                                    int2* __restrict__ bbuf,
                                                    int E, int NB, int ntiles) {
    extern __shared__ int cur[];   // NB ints
    int t = blockIdx.x;
    int lo = t * PTILE;
    int hi = lo + PTILE; if (hi > E) hi = E;
    for (int b = threadIdx.x; b < NB; b += 1024) cur[b] = tbase[b * ntiles + t];
    __syncthreads();
    for (int i = lo + threadIdx.x; i < hi; i += 1024) {
        int d = edst[i];
        int b = d >> BSH;
        int p = atomicAdd(&cur[b], 1);
        bbuf[p] = make_int2(esrc[i] | ((d & (BW - 1)) << 18), __float_as_int(ew[i]));
    }
}

// per-bucket LDS counting sort (512 local nodes) -> dst-sorted edata + rowptr
__global__ __launch_bounds__(1024) void lg_bfinal(const int2* __restrict__ bbuf,
                                                  const int* __restrict__ tbase,
                                                  int2* __restrict__ edata,
                                                  int* __restrict__ rowptr,
                                                  int n_nodes, int NB, int ntiles, int E) {
    __shared__ int cnt[BW];
    __shared__ int cur[BW];
    __shared__ int psum[BW];
    int b = blockIdx.x;
    int s = tbase[b * ntiles];
    int e = (b == NB - 1) ? E : tbase[(b + 1) * ntiles];
    int tid = threadIdx.x;
    if (tid < BW) cnt[tid] = 0;
    __syncthreads();
    for (int i = s + tid; i < e; i += 1024)
        atomicAdd(&cnt[((unsigned)bbuf[i].x >> 18) & (BW - 1)], 1);
    __syncthreads();
    if (tid < BW) psum[tid] = cnt[tid];
    __syncthreads();
    for (int off = 1; off < BW; off <<= 1) {
        int v = 0;
        if (tid < BW && tid >= off) v = psum[tid - off];
        __syncthreads();
        if (tid < BW) psum[tid] += v;
        __syncthreads();
    }
    if (tid < BW) {
        int excl = psum[tid] - cnt[tid];
        cur[tid] = excl;
        int node = b * BW + tid;
        if (node < n_nodes) rowptr[node] = s + excl;
    }
    __syncthreads();
    for (int i = s + tid; i < e; i += 1024) {
        int2 ed = bbuf[i];
        int loc = ((unsigned)ed.x >> 18) & (BW - 1);
        int p = s + atomicAdd(&cur[loc], 1);
        edata[p] = make_int2(ed.x & 0x3FFFF, ed.y);
    }
}

// gather SpMM (fp16 x): wave per dst node, quarter-wave per edge.
// lane = (q = edge slot 0..3, c = 8-byte chunk 0..15): each lane loads 4 halves.
template <bool FIRST, bool LAST>
__global__ __launch_bounds__(256) void lg_gather(const int2* __restrict__ edata,
                                                 const int* __restrict__ rowptr,
                                                 const __half* __restrict__ x,
                                                 __half* __restrict__ y,
                                                 float* __restrict__ acc,
                                                 const float* __restrict__ ini,
                                                 int n_nodes) {
    int wid = (blockIdx.x * blockDim.x + threadIdx.x) >> 6;
    int lane = threadIdx.x & 63;
    if (wid >= n_nodes) return;
    int q = lane >> 4, c = lane & 15;
    int start = rowptr[wid], end = rowptr[wid + 1];
    float ax = 0.f, ay = 0.f, az = 0.f, aw = 0.f;
    int base = start;
    for (; base + 16 <= end; base += 16) {
        int2 e0 = edata[base + q];
        int2 e1 = edata[base + 4 + q];
        int2 e2 = edata[base + 8 + q];
        int2 e3 = edata[base + 12 + q];
        uint2 u0 = *((const uint2*)(x + (size_t)e0.x * D) + c);
        uint2 u1 = *((const uint2*)(x + (size_t)e1.x * D) + c);
        uint2 u2 = *((const uint2*)(x + (size_t)e2.x * D) + c);
        uint2 u3 = *((const uint2*)(x + (size_t)e3.x * D) + c);
        float w0 = __int_as_float(e0.y), w1 = __int_as_float(e1.y);
        float w2 = __int_as_float(e2.y), w3 = __int_as_float(e3.y);
        {
            float2 f0 = __half22float2(*reinterpret_cast<__half2*>(&u0.x));
            float2 f1 = __half22float2(*reinterpret_cast<__half2*>(&u0.y));
            ax += w0 * f0.x; ay += w0 * f0.y; az += w0 * f1.x; aw += w0 * f1.y;
        }
        {
            float2 f0 = __half22float2(*reinterpret_cast<__half2*>(&u1.x));
            float2 f1 = __half22float2(*reinterpret_cast<__half2*>(&u1.y));
            ax += w1 * f0.x; ay += w1 * f0.y; az += w1 * f1.x; aw += w1 * f1.y;
        }
        {
            float2 f0 = __half22float2(*reinterpret_cast<__half2*>(&u2.x));
            float2 f1 = __half22float2(*reinterpret_cast<__half2*>(&u2.y));
            ax += w2 * f0.x; ay += w2 * f0.y; az += w2 * f1.x; aw += w2 * f1.y;
        }
        {
            float2 f0 = __half22float2(*reinterpret_cast<__half2*>(&u3.x));
            float2 f1 = __half22float2(*reinterpret_cast<__half2*>(&u3.y));
            ax += w3 * f0.x; ay += w3 * f0.y; az += w3 * f1.x; aw += w3 * f1.y;
        }
    }
    for (; base < end; base += 4) {
        int idx = base + q;
        if (idx < end) {
            int2 e0 = edata[idx];
            float w0 = __int_as_float(e0.y);
            uint2 u0 = *((const uint2*)(x + (size_t)e0.x * D) + c);
            float2 f0 = __half22float2(*reinterpret_cast<__half2*>(&u0.x));
            float2 f1 = __half22float2(*reinterpret_cast<__half2*>(&u0.y));
            ax += w0 * f0.x; ay += w0 * f0.y; az += w0 * f1.x; aw += w0 * f1.y;
        }
    }
    ax += __shfl_xor(ax, 16); ax += __shfl_xor(ax, 32);
    ay += __shfl_xor(ay, 16); ay += __shfl_xor(ay, 32);
    az += __shfl_xor(az, 16); az += __shfl_xor(az, 32);
    aw += __shfl_xor(aw, 16); aw += __shfl_xor(aw, 32);
    if (lane < 16) {
        size_t o = (size_t)wid * D + (size_t)c * 4;
        if (!LAST) {
            __half2 h0 = __floats2half2_rn(ax, ay);
            __half2 h1 = __floats2half2_rn(az, aw);
            uint2 u;
            u.x = *reinterpret_cast<unsigned int*>(&h0);
            u.y = *reinterpret_cast<unsigned int*>(&h1);
            *(uint2*)(y + o) = u;
        }
        if (FIRST) {
            float4 iv = *(const float4*)(ini + o);
            *(float4*)(acc + o) = make_float4(iv.x + ax, iv.y + ay, iv.z + az, iv.w + aw);
        } else {
            float4 av = *(float4*)(acc + o);
            *(float4*)(acc + o) = make_float4(av.x + ax, av.y + ay, av.z + az, av.w + aw);
        }
    }
}

// fallback (atomic scatter path, only if ws too small)
__global__ void lg_init_kernel(const float* __restrict__ ini, float* __restrict__ cur,
                               float* __restrict__ acc, float* __restrict__ nxt, int n4) {
    int i = blockIdx.x * blockDim.x + threadIdx.x;
    int stride = gridDim.x * blockDim.x;
    const float4* s = (const float4*)ini;
    float4* c = (float4*)cur; float4* a = (float4*)acc; float4* z = (float4*)nxt;
    float4 zero = make_float4(0.f, 0.f, 0.f, 0.f);
    for (; i < n4; i += stride) { float4 v = s[i]; c[i] = v; a[i] = v; z[i] = zero; }
}

__global__ void lg_spmm_kernel(const int* __restrict__ esrc, const int* __restrict__ edst,
                               const float* __restrict__ ew, const float* __restrict__ x,
                               float* __restrict__ y, int E) {
    int tid = blockIdx.x * blockDim.x + threadIdx.x;
    int e = tid >> 4;
    if (e >= E) return;
    int l = (tid & 15) << 2;
    int s = esrc[e]; int d = edst[e]; float w = ew[e];
    float4 v = *(const float4*)(x + s * D + l);
    float* yp = y + d * D + l;
    unsafeAtomicAdd(yp + 0, w * v.x);
    unsafeAtomicAdd(yp + 1, w * v.y);
    unsafeAtomicAdd(yp + 2, w * v.z);
    unsafeAtomicAdd(yp + 3, w * v.w);
}

__global__ void lg_addzero_kernel(float* __restrict__ acc, const float* __restrict__ nxt,
                                  float* __restrict__ zbuf, int n4) {
    int i = blockIdx.x * blockDim.x + threadIdx.x;
    int stride = gridDim.x * blockDim.x;
    float4* a = (float4*)acc; const float4* n = (const float4*)nxt; float4* z = (float4*)zbuf;
    float4 zero = make_float4(0.f, 0.f, 0.f, 0.f);
    for (; i < n4; i += stride) {
        float4 av = a[i]; float4 nv = n[i];
        av.x += nv.x; av.y += nv.y; av.z += nv.z; av.w += nv.w;
        a[i] = av; z[i] = zero;
    }
}

extern "C" void kernel_launch(void* const* d_in, const int* in_sizes, int n_in,
                              void* d_out, int out_size, void* d_ws, size_t ws_size,
                              hipStream_t stream) {
    const float* ini  = (const float*)d_in[0];
    const int*   esrc = (const int*)d_in[1];
    const int*   edst = (const int*)d_in[2];
    const float* ew   = (const float*)d_in[3];

    int n_nodes = in_sizes[0] / D;     // 150000
    int E       = in_sizes[1];         // 4.8M
    int NB      = (n_nodes + BW - 1) >> BSH;        // 293
    int ntiles  = (E + PTILE - 1) / PTILE;          // 293
    int NT      = NB * ntiles;                      // 85849
    int nscan   = (NT + 1023) / 1024;               // 84  (<=128 required)

    size_t hBytes     = ((size_t)n_nodes * D * sizeof(__half) + 255) & ~(size_t)255;  // 19.2 MB
    size_t edataBytes = (size_t)E * sizeof(int2);                                     // 38.4 MB
    size_t ptrBytes   = (((size_t)n_nodes + 1) * 4 + 15) & ~(size_t)15;
    size_t tcntBytes  = (((size_t)NT * 4) + 15) & ~(size_t)15;
    size_t blkBytes   = (128 * 4 + 15) & ~(size_t)15;
    size_t need = 2 * hBytes + 2 * edataBytes + ptrBytes + 2 * tcntBytes + blkBytes + 64;

    float* acc = (float*)d_out;

    if (ws_size >= need && nscan <= 128) {
        char* p = (char*)d_ws;
        __half* h0    = (__half*)p; p += hBytes;
        __half* h1    = (__half*)p; p += hBytes;
        int2*  edata  = (int2*)p;   p += edataBytes;
        int2*  bbuf   = (int2*)p;   p += edataBytes;
        int*   rowptr = (int*)p;    p += ptrBytes;
        int*   tcnt   = (int*)p;    p += tcntBytes;
        int*   tbase  = (int*)p;    p += tcntBytes;
        int*   blksum = (int*)p;

        int n4 = n_nodes * D / 4;

        lg_f2h<<<2048, 256, 0, stream>>>(ini, h0, n4);
        lg_tilehist<<<ntiles, 1024, (size_t)NB * 4, stream>>>(edst, tcnt, E, NB, ntiles);
        lg_scan1<<<nscan, 1024, 0, stream>>>(tcnt, tbase, blksum, NT);
        lg_scan2<<<1, 128, 0, stream>>>(blksum, nscan, rowptr, n_nodes, E);
        lg_scan3<<<nscan, 1024, 0, stream>>>(tbase, blksum, NT);
        lg_scatter2<<<ntiles, 1024, (size_t)NB * 4, stream>>>(esrc, edst, ew, tbase, bbuf, E, NB, ntiles);
        lg_bfinal<<<NB, 1024, 0, stream>>>(bbuf, tbase, edata, rowptr, n_nodes, NB, ntiles, E);

        int gblocks = (int)(((size_t)n_nodes * 64 + 255) / 256);
        lg_gather<true,  false><<<gblocks, 256, 0, stream>>>(edata, rowptr, h0, h1, acc, ini, n_nodes);
        lg_gather<false, false><<<gblocks, 256, 0, stream>>>(edata, rowptr, h1, h0, acc, ini, n_nodes);
        lg_gather<false, true ><<<gblocks, 256, 0, stream>>>(edata, rowptr, h0, h1, acc, ini, n_nodes);
    } else {
        int n4 = (n_nodes * D) / 4;
        float* cur = (float*)d_ws;
        float* nxt = cur + (size_t)n_nodes * D;
        lg_init_kernel<<<2048, 256, 0, stream>>>(ini, cur, acc, nxt, n4);
        int spmm_blocks = (E * 16 + 255) / 256;
        for (int layer = 0; layer < 3; ++layer) {
            lg_spmm_kernel<<<spmm_blocks, 256, 0, stream>>>(esrc, edst, ew, cur, nxt, E);
            lg_addzero_kernel<<<2048, 256, 0, stream>>>(acc, nxt, cur, n4);
            float* t = cur; cur = nxt; nxt = t;
        }
    }
}

// Round 8
// 404.522 us; speedup vs baseline: 1.3666x; 1.1211x over previous
//
#include <hip/hip_runtime.h>
#include <hip/hip_fp16.h>

// LightGCN forward: acc = sum over layers of (A^l @ X), A sparse COO (src,dst,w).
// Build dst-sorted CSR once per launch, atomic-free and deterministic:
//   lg_tilehist      : per-tile LDS histogram -> tcnt[bucket][tile]  (bucket-major)
//   lg_scan1/2/3     : hierarchical exclusive scan over tcnt -> tbase
//   lg_scatter2      : scatter edges into contiguous per-(tile,bucket) runs (LDS cursors)
//   lg_bfinal        : per-bucket (512-node) LDS counting sort -> dst-sorted edata + rowptr
// Then 3 gather SpMM layers; layer embeddings staged FP16 (v_fma_mix accumulate
// into FP32), accumulator/output FP32.

#define D 64
#define BSH 9
#define BW 512            // nodes per bucket = 1<<BSH
#define PTILE 16384       // edges per partition tile

// fp16(lo/hi of 32-bit reg) * fp32 + fp32 in one VOP3P instruction
#define MIXLO(acc, reg, w) \
    asm("v_fma_mix_f32 %0, %1, %2, %0 op_sel:[0,0,0] op_sel_hi:[1,0,0]" \
        : "+v"(acc) : "v"(reg), "v"(w))
#define MIXHI(acc, reg, w) \
    asm("v_fma_mix_f32 %0, %1, %2, %0 op_sel:[1,0,0] op_sel_hi:[1,0,0]" \
        : "+v"(acc) : "v"(reg), "v"(w))

// fp32 -> fp16 conversion (4 floats / thread)
__global__ void lg_f2h(const float* __restrict__ in, __half* __restrict__ out, int n4) {
    int i = blockIdx.x * blockDim.x + threadIdx.x;
    int st = gridDim.x * blockDim.x;
    const float4* src = (const float4*)in;
    uint2* dst = (uint2*)out;
    for (; i < n4; i += st) {
        float4 v = src[i];
        __half2 a = __floats2half2_rn(v.x, v.y);
        __half2 b = __floats2half2_rn(v.z, v.w);
        uint2 u;
        u.x = *reinterpret_cast<unsigned int*>(&a);
        u.y = *reinterpret_cast<unsigned int*>(&b);
        dst[i] = u;
    }
}

// per-tile bucket histogram -> tcnt[b*ntiles + t]
__global__ __launch_bounds__(1024) void lg_tilehist(const int* __restrict__ edst,
                                                    int* __restrict__ tcnt,
                                                    int E, int NB, int ntiles) {
    extern __shared__ int cnt[];   // NB ints
    int t = blockIdx.x;
    int lo = t * PTILE;
    int hi = lo + PTILE; if (hi > E) hi = E;
    for (int i = threadIdx.x; i < NB; i += 1024) cnt[i] = 0;
    __syncthreads();
    for (int i = lo + threadIdx.x; i < hi; i += 1024)
        atomicAdd(&cnt[edst[i] >> BSH], 1);
    __syncthreads();
    for (int b = threadIdx.x; b < NB; b += 1024)
        tcnt[b * ntiles + t] = cnt[b];
}

// scan stage 1: per-block LDS scan of 1024 entries; exclusive -> tbase, total -> blksum
__global__ __launch_bounds__(1024) void lg_scan1(const int* __restrict__ tcnt,
                                                 int* __restrict__ tbase,
                                                 int* __restrict__ blksum, int NT) {
    __shared__ int lds[1024];
    int tid = threadIdx.x;
    int i = blockIdx.x * 1024 + tid;
    int v = (i < NT) ? tcnt[i] : 0;
    lds[tid] = v;
    __syncthreads();
    for (int off = 1; off < 1024; off <<= 1) {
        int t = (tid >= off) ? lds[tid - off] : 0;
        __syncthreads();
        lds[tid] += t;
        __syncthreads();
    }
    if (i < NT) tbase[i] = lds[tid] - v;
    if (tid == 1023) blksum[blockIdx.x] = lds[tid];
}

// scan stage 2: exclusive scan of block sums (nblk <= 128); also seeds rowptr[n]
__global__ __launch_bounds__(128) void lg_scan2(int* __restrict__ blksum, int nblk,
                                                int* __restrict__ rowptr, int n_nodes, int E) {
    __shared__ int lds[128];
    int tid = threadIdx.x;
    int v = (tid < nblk) ? blksum[tid] : 0;
    lds[tid] = v;
    __syncthreads();
    for (int off = 1; off < 128; off <<= 1) {
        int t = (tid >= off) ? lds[tid - off] : 0;
        __syncthreads();
        lds[tid] += t;
        __syncthreads();
    }
    if (tid < nblk) blksum[tid] = lds[tid] - v;   // exclusive
    if (tid == 0) rowptr[n_nodes] = E;
}

// scan stage 3: add block offsets
__global__ __launch_bounds__(1024) void lg_scan3(int* __restrict__ tbase,
                                                 const int* __restrict__ blksum, int NT) {
    int add = blksum[blockIdx.x];
    int i = blockIdx.x * 1024 + threadIdx.x;
    if (i < NT) tbase[i] += add;
}

// scatter edges into their (tile,bucket) runs; LDS cursors, no global atomics.
// record: {src | (dst&511)<<18, w_bits}; src<2^18 ok for n_nodes=150000.
__global__ __launch_bounds__(1024) void lg_scatter2(const int* __restrict__ esrc,
                                                    const int* __restrict__ edst,
                                                    const float* __restrict__ ew,
                                                    const int* __restrict__ tbase,
                                                    int2* __restrict__ bbuf,
                                                    int E, int NB, int ntiles) {
    extern __shared__ int cur[];   // NB ints
    int t = blockIdx.x;
    int lo = t * PTILE;
    int hi = lo + PTILE; if (hi > E) hi = E;
    for (int b = threadIdx.x; b < NB; b += 1024) cur[b] = tbase[b * ntiles + t];
    __syncthreads();
    for (int i = lo + threadIdx.x; i < hi; i += 1024) {
        int d = edst[i];
        int b = d >> BSH;
        int p = atomicAdd(&cur[b], 1);
        bbuf[p] = make_int2(esrc[i] | ((d & (BW - 1)) << 18), __float_as_int(ew[i]));
    }
}

// per-bucket LDS counting sort (512 local nodes) -> dst-sorted edata + rowptr
__global__ __launch_bounds__(1024) void lg_bfinal(const int2* __restrict__ bbuf,
                                                  const int* __restrict__ tbase,
                                                  int2* __restrict__ edata,
                                                  int* __restrict__ rowptr,
                                                  int n_nodes, int NB, int ntiles, int E) {
    __shared__ int cnt[BW];
    __shared__ int cur[BW];
    __shared__ int psum[BW];
    int b = blockIdx.x;
    int s = tbase[b * ntiles];
    int e = (b == NB - 1) ? E : tbase[(b + 1) * ntiles];
    int tid = threadIdx.x;
    if (tid < BW) cnt[tid] = 0;
    __syncthreads();
    for (int i = s + tid; i < e; i += 1024)
        atomicAdd(&cnt[((unsigned)bbuf[i].x >> 18) & (BW - 1)], 1);
    __syncthreads();
    if (tid < BW) psum[tid] = cnt[tid];
    __syncthreads();
    for (int off = 1; off < BW; off <<= 1) {
        int v = 0;
        if (tid < BW && tid >= off) v = psum[tid - off];
        __syncthreads();
        if (tid < BW) psum[tid] += v;
        __syncthreads();
    }
    if (tid < BW) {
        int excl = psum[tid] - cnt[tid];
        cur[tid] = excl;
        int node = b * BW + tid;
        if (node < n_nodes) rowptr[node] = s + excl;
    }
    __syncthreads();
    for (int i = s + tid; i < e; i += 1024) {
        int2 ed = bbuf[i];
        int loc = ((unsigned)ed.x >> 18) & (BW - 1);
        int p = s + atomicAdd(&cur[loc], 1);
        edata[p] = make_int2(ed.x & 0x3FFFF, ed.y);
    }
}

// gather SpMM (fp16 x): wave per dst node, 8-lane group per edge.
// lane = (o = edge slot 0..7, c = 16-byte chunk 0..7): each lane loads 8 halves
// as uint4 and accumulates 8 fp32 components via v_fma_mix.
template <bool FIRST, bool LAST>
__global__ __launch_bounds__(256) void lg_gather(const int2* __restrict__ edata,
                                                 const int* __restrict__ rowptr,
                                                 const __half* __restrict__ x,
                                                 __half* __restrict__ y,
                                                 float* __restrict__ acc,
                                                 const float* __restrict__ ini,
                                                 int n_nodes) {
    int wid = (blockIdx.x * blockDim.x + threadIdx.x) >> 6;
    int lane = threadIdx.x & 63;
    if (wid >= n_nodes) return;
    int o = lane >> 3, c = lane & 7;
    int start = rowptr[wid], end = rowptr[wid + 1];
    float a0 = 0.f, a1 = 0.f, a2 = 0.f, a3 = 0.f;
    float a4 = 0.f, a5 = 0.f, a6 = 0.f, a7 = 0.f;
    int base = start;
    for (; base + 16 <= end; base += 16) {
        int2 e0 = edata[base + o];
        int2 e1 = edata[base + 8 + o];
        uint4 u0 = *((const uint4*)(x + (size_t)e0.x * D) + c);
        uint4 u1 = *((const uint4*)(x + (size_t)e1.x * D) + c);
        float w0 = __int_as_float(e0.y);
        float w1 = __int_as_float(e1.y);
        MIXLO(a0, u0.x, w0); MIXHI(a1, u0.x, w0);
        MIXLO(a2, u0.y, w0); MIXHI(a3, u0.y, w0);
        MIXLO(a4, u0.z, w0); MIXHI(a5, u0.z, w0);
        MIXLO(a6, u0.w, w0); MIXHI(a7, u0.w, w0);
        MIXLO(a0, u1.x, w1); MIXHI(a1, u1.x, w1);
        MIXLO(a2, u1.y, w1); MIXHI(a3, u1.y, w1);
        MIXLO(a4, u1.z, w1); MIXHI(a5, u1.z, w1);
        MIXLO(a6, u1.w, w1); MIXHI(a7, u1.w, w1);
    }
    for (; base < end; base += 8) {
        int idx = base + o;
        if (idx < end) {
            int2 e0 = edata[idx];
            uint4 u0 = *((const uint4*)(x + (size_t)e0.x * D) + c);
            float w0 = __int_as_float(e0.y);
            MIXLO(a0, u0.x, w0); MIXHI(a1, u0.x, w0);
            MIXLO(a2, u0.y, w0); MIXHI(a3, u0.y, w0);
            MIXLO(a4, u0.z, w0); MIXHI(a5, u0.z, w0);
            MIXLO(a6, u0.w, w0); MIXHI(a7, u0.w, w0);
        }
    }
    // reduce across edge slots (lane bits 3..5)
    a0 += __shfl_xor(a0, 8); a0 += __shfl_xor(a0, 16); a0 += __shfl_xor(a0, 32);
    a1 += __shfl_xor(a1, 8); a1 += __shfl_xor(a1, 16); a1 += __shfl_xor(a1, 32);
    a2 += __shfl_xor(a2, 8); a2 += __shfl_xor(a2, 16); a2 += __shfl_xor(a2, 32);
    a3 += __shfl_xor(a3, 8); a3 += __shfl_xor(a3, 16); a3 += __shfl_xor(a3, 32);
    a4 += __shfl_xor(a4, 8); a4 += __shfl_xor(a4, 16); a4 += __shfl_xor(a4, 32);
    a5 += __shfl_xor(a5, 8); a5 += __shfl_xor(a5, 16); a5 += __shfl_xor(a5, 32);
    a6 += __shfl_xor(a6, 8); a6 += __shfl_xor(a6, 16); a6 += __shfl_xor(a6, 32);
    a7 += __shfl_xor(a7, 8); a7 += __shfl_xor(a7, 16); a7 += __shfl_xor(a7, 32);
    if (lane < 8) {
        size_t o32 = (size_t)wid * D + (size_t)c * 8;    // float offset
        if (!LAST) {
            __half2 h0 = __floats2half2_rn(a0, a1);
            __half2 h1 = __floats2half2_rn(a2, a3);
            __half2 h2 = __floats2half2_rn(a4, a5);
            __half2 h3 = __floats2half2_rn(a6, a7);
            uint4 u;
            u.x = *reinterpret_cast<unsigned int*>(&h0);
            u.y = *reinterpret_cast<unsigned int*>(&h1);
            u.z = *reinterpret_cast<unsigned int*>(&h2);
            u.w = *reinterpret_cast<unsigned int*>(&h3);
            *((uint4*)(y + (size_t)wid * D) + c) = u;
        }
        const float* rsrc = FIRST ? (ini + o32) : (acc + o32);
        float4 r0 = *(const float4*)(rsrc);
        float4 r1 = *(const float4*)(rsrc + 4);
        *(float4*)(acc + o32)     = make_float4(r0.x + a0, r0.y + a1, r0.z + a2, r0.w + a3);
        *(float4*)(acc + o32 + 4) = make_float4(r1.x + a4, r1.y + a5, r1.z + a6, r1.w + a7);
    }
}

// fallback (atomic scatter path, only if ws too small)
__global__ void lg_init_kernel(const float* __restrict__ ini, float* __restrict__ cur,
                               float* __restrict__ acc, float* __restrict__ nxt, int n4) {
    int i = blockIdx.x * blockDim.x + threadIdx.x;
    int stride = gridDim.x * blockDim.x;
    const float4* s = (const float4*)ini;
    float4* c = (float4*)cur; float4* a = (float4*)acc; float4* z = (float4*)nxt;
    float4 zero = make_float4(0.f, 0.f, 0.f, 0.f);
    for (; i < n4; i += stride) { float4 v = s[i]; c[i] = v; a[i] = v; z[i] = zero; }
}

__global__ void lg_spmm_kernel(const int* __restrict__ esrc, const int* __restrict__ edst,
                               const float* __restrict__ ew, const float* __restrict__ x,
                               float* __restrict__ y, int E) {
    int tid = blockIdx.x * blockDim.x + threadIdx.x;
    int e = tid >> 4;
    if (e >= E) return;
    int l = (tid & 15) << 2;
    int s = esrc[e]; int d = edst[e]; float w = ew[e];
    float4 v = *(const float4*)(x + s * D + l);
    float* yp = y + d * D + l;
    unsafeAtomicAdd(yp + 0, w * v.x);
    unsafeAtomicAdd(yp + 1, w * v.y);
    unsafeAtomicAdd(yp + 2, w * v.z);
    unsafeAtomicAdd(yp + 3, w * v.w);
}

__global__ void lg_addzero_kernel(float* __restrict__ acc, const float* __restrict__ nxt,
                                  float* __restrict__ zbuf, int n4) {
    int i = blockIdx.x * blockDim.x + threadIdx.x;
    int stride = gridDim.x * blockDim.x;
    float4* a = (float4*)acc; const float4* n = (const float4*)nxt; float4* z = (float4*)zbuf;
    float4 zero = make_float4(0.f, 0.f, 0.f, 0.f);
    for (; i < n4; i += stride) {
        float4 av = a[i]; float4 nv = n[i];
        av.x += nv.x; av.y += nv.y; av.z += nv.z; av.w += nv.w;
        a[i] = av; z[i] = zero;
    }
}

extern "C" void kernel_launch(void* const* d_in, const int* in_sizes, int n_in,
                              void* d_out, int out_size, void* d_ws, size_t ws_size,
                              hipStream_t stream) {
    const float* ini  = (const float*)d_in[0];
    const int*   esrc = (const int*)d_in[1];
    const int*   edst = (const int*)d_in[2];
    const float* ew   = (const float*)d_in[3];

    int n_nodes = in_sizes[0] / D;     // 150000
    int E       = in_sizes[1];         // 4.8M
    int NB      = (n_nodes + BW - 1) >> BSH;        // 293
    int ntiles  = (E + PTILE - 1) / PTILE;          // 293
    int NT      = NB * ntiles;                      // 85849
    int nscan   = (NT + 1023) / 1024;               // 84  (<=128 required)

    size_t hBytes     = ((size_t)n_nodes * D * sizeof(__half) + 255) & ~(size_t)255;  // 19.2 MB
    size_t edataBytes = (size_t)E * sizeof(int2);                                     // 38.4 MB
    size_t ptrBytes   = (((size_t)n_nodes + 1) * 4 + 15) & ~(size_t)15;
    size_t tcntBytes  = (((size_t)NT * 4) + 15) & ~(size_t)15;
    size_t blkBytes   = (128 * 4 + 15) & ~(size_t)15;
    size_t need = 2 * hBytes + 2 * edataBytes + ptrBytes + 2 * tcntBytes + blkBytes + 64;

    float* acc = (float*)d_out;

    if (ws_size >= need && nscan <= 128) {
        char* p = (char*)d_ws;
        __half* h0    = (__half*)p; p += hBytes;
        __half* h1    = (__half*)p; p += hBytes;
        int2*  edata  = (int2*)p;   p += edataBytes;
        int2*  bbuf   = (int2*)p;   p += edataBytes;
        int*   rowptr = (int*)p;    p += ptrBytes;
        int*   tcnt   = (int*)p;    p += tcntBytes;
        int*   tbase  = (int*)p;    p += tcntBytes;
        int*   blksum = (int*)p;

        int n4 = n_nodes * D / 4;

        lg_f2h<<<2048, 256, 0, stream>>>(ini, h0, n4);
        lg_tilehist<<<ntiles, 1024, (size_t)NB * 4, stream>>>(edst, tcnt, E, NB, ntiles);
        lg_scan1<<<nscan, 1024, 0, stream>>>(tcnt, tbase, blksum, NT);
        lg_scan2<<<1, 128, 0, stream>>>(blksum, nscan, rowptr, n_nodes, E);
        lg_scan3<<<nscan, 1024, 0, stream>>>(tbase, blksum, NT);
        lg_scatter2<<<ntiles, 1024, (size_t)NB * 4, stream>>>(esrc, edst, ew, tbase, bbuf, E, NB, ntiles);
        lg_bfinal<<<NB, 1024, 0, stream>>>(bbuf, tbase, edata, rowptr, n_nodes, NB, ntiles, E);

        int gblocks = (int)(((size_t)n_nodes * 64 + 255) / 256);
        lg_gather<true,  false><<<gblocks, 256, 0, stream>>>(edata, rowptr, h0, h1, acc, ini, n_nodes);
        lg_gather<false, false><<<gblocks, 256, 0, stream>>>(edata, rowptr, h1, h0, acc, ini, n_nodes);
        lg_gather<false, true ><<<gblocks, 256, 0, stream>>>(edata, rowptr, h0, h1, acc, ini, n_nodes);
    } else {
        int n4 = (n_nodes * D) / 4;
        float* cur = (float*)d_ws;
        float* nxt = cur + (size_t)n_nodes * D;
        lg_init_kernel<<<2048, 256, 0, stream>>>(ini, cur, acc, nxt, n4);
        int spmm_blocks = (E * 16 + 255) / 256;
        for (int layer = 0; layer < 3; ++layer) {
            lg_spmm_kernel<<<spmm_blocks, 256, 0, stream>>>(esrc, edst, ew, cur, nxt, E);
            lg_addzero_kernel<<<2048, 256, 0, stream>>>(acc, nxt, cur, n4);
            float* t = cur; cur = nxt; nxt = t;
        }
    }
}